// Round 4
// baseline (238.011 us; speedup 1.0000x reference)
//
#include <hip/hip_runtime.h>
#include <hip/hip_bf16.h>
#include <stdint.h>

// Shapes (fixed): B=4, N=8, Q=256, K=1024, D_MODEL=512, H=8, Dh=64, R=8, sigma=0.05

typedef __attribute__((ext_vector_type(8))) short bf16x8;
typedef __attribute__((ext_vector_type(4))) float f32x4;
typedef __attribute__((ext_vector_type(2))) float f32x2;

__device__ __forceinline__ unsigned short f2b(float f){
    unsigned int u = __builtin_bit_cast(unsigned int, f);
    unsigned int r = u + 0x7fffu + ((u >> 16) & 1u);   // RNE
    return (unsigned short)(r >> 16);
}

// packed f32->bf16x2 (RNE), single HW instr
__device__ __forceinline__ unsigned cvtpk2(float lo, float hi){
    unsigned r;
    asm("v_cvt_pk_bf16_f32 %0, %1, %2" : "=v"(r) : "v"(lo), "v"(hi));
    return r;
}

// two-level XOR swizzle for 64-col bf16 LDS tiles (128B rows): conflict-free
// for row-wise b64/b128 staging writes, b128 fragment reads, and b16 scatter.
__device__ __forceinline__ int swzT(int row, int byteInRow){
    return row*128 + (byteInRow ^ (((row ^ (row >> 3)) & 7) << 4));
}

// DPP cross-lane (within 16-lane row): 0xB1=xor1, 0x4E=xor2, 0x141=xor7, 0x140=xor15
template<int CTRL>
__device__ __forceinline__ float dpp_mov(float x){
    return __builtin_bit_cast(float,
        __builtin_amdgcn_update_dpp(0, __builtin_bit_cast(int, x), CTRL, 0xF, 0xF, true));
}
__device__ __forceinline__ float grp16_max(float x){
    x = fmaxf(x, dpp_mov<0xB1>(x));
    x = fmaxf(x, dpp_mov<0x4E>(x));
    x = fmaxf(x, dpp_mov<0x141>(x));
    x = fmaxf(x, dpp_mov<0x140>(x));
    return x;
}
__device__ __forceinline__ float grp16_sum(float x){
    x += dpp_mov<0xB1>(x);
    x += dpp_mov<0x4E>(x);
    x += dpp_mov<0x141>(x);
    x += dpp_mov<0x140>(x);
    return x;
}

// ---------------- all 4 weight transposes in one launch ---------------------
__global__ __launch_bounds__(256) void wt4_kernel(
    const float* __restrict__ Wq, const float* __restrict__ Wk,
    const float* __restrict__ Wv, const float* __restrict__ Wo,
    unsigned short* __restrict__ WtBase){
    __shared__ float tile[64][65];
    int kt = blockIdx.x, nt = blockIdx.y, wsel = blockIdx.z;
    const float* W = (wsel == 0) ? Wq : (wsel == 1) ? Wk : (wsel == 2) ? Wv : Wo;
    unsigned short* Wt = WtBase + (size_t)wsel * 262144;
    int tid = threadIdx.x;
    #pragma unroll
    for(int it=0; it<16; ++it){
        int idx = it*256 + tid;
        int r = idx >> 6, c = idx & 63;
        tile[r][c] = W[(kt*64 + r)*512 + nt*64 + c];
    }
    __syncthreads();
    #pragma unroll
    for(int it=0; it<16; ++it){
        int idx = it*256 + tid;
        int r = idx >> 6, c = idx & 63;
        Wt[(nt*64 + r)*512 + kt*64 + c] = f2b(tile[c][r]);
    }
}

// ---------------- positional features (rank-3 collapsed bias) ---------------
__global__ __launch_bounds__(256) void posfeat_kernel(
    const float* __restrict__ qpos, const float* __restrict__ kpos,
    const float* __restrict__ Wqb,  const float* __restrict__ Wkb,
    const int* __restrict__ mask,
    float* __restrict__ qwg,        // [1024][4]
    float* __restrict__ kfg){       // [4096][4]
    const float L2E = 1.4426950408889634f;
    const float S8  = 0.35355339059327373f;
    int id = blockIdx.x*256 + threadIdx.x;
    if(id < 1024){
        const float* p = qpos + id*3;
        float x = p[0], y = p[1], z = p[2];
        float qw0 = 400.f*x, qw1 = 400.f*y, qw2 = 400.f*z;
        #pragma unroll
        for(int r=0;r<8;++r){
            float qb = x*Wqb[r] + y*Wqb[8+r] + z*Wqb[16+r];
            float c  = S8*qb;
            qw0 += c*Wkb[r];
            qw1 += c*Wkb[8+r];
            qw2 += c*Wkb[16+r];
        }
        float4 o = {L2E*qw0, L2E*qw1, L2E*qw2, 0.f};
        *reinterpret_cast<float4*>(qwg + (size_t)id*4) = o;
    } else if(id < 5120){
        int k = id - 1024;
        const float* p = kpos + k*3;
        float x = p[0], y = p[1], z = p[2];
        float n2 = -200.0f*(x*x + y*y + z*z)*L2E;
        int mk = mask[k];
        float4 o = {x, y, z, mk ? n2 : -3.0e38f};
        *reinterpret_cast<float4*>(kfg + (size_t)k*4) = o;
    }
}

// ---------------- fused K+V projection GEMM ---------------------------------
// C_K[m][512] -> kp (row-major bf16); C_V -> vpT transposed per-head:
// vpT[(z*8+h)*64+d][1024 kpos]. A staged once.
__global__ __launch_bounds__(256) void gemm_kv(
    const float* __restrict__ A,
    const unsigned short* __restrict__ BtK,
    const unsigned short* __restrict__ BtV,
    const float* __restrict__ bkv, const float* __restrict__ bvv,
    unsigned short* __restrict__ kp,
    unsigned short* __restrict__ vpT){
    __shared__ alignas(16) char sm[49152];
    char* As  = sm;
    char* BsK = sm + 16384;
    char* BsV = sm + 32768;
    int n0 = blockIdx.x * 128, m0 = blockIdx.y * 128;
    int tid = threadIdx.x;
    int l = tid & 63, wid = tid >> 6;
    int wr = wid >> 1, wc = wid & 1;
    int l15 = l & 15, lg = l >> 4;

    f32x4 acck[4][4], accv[4][4];
    const f32x4 z4 = {0.f,0.f,0.f,0.f};
    #pragma unroll
    for(int m=0;m<4;++m)
        #pragma unroll
        for(int n=0;n<4;++n){ acck[m][n] = z4; accv[m][n] = z4; }

    for(int kt=0; kt<8; ++kt){
        int k0 = kt*64;
        __syncthreads();
        #pragma unroll
        for(int it=0; it<8; ++it){
            int idx = it*256 + tid;
            int row = idx >> 4;
            int col = (idx & 15) * 4;
            float4 v = *reinterpret_cast<const float4*>(A + (size_t)(m0+row)*512 + k0 + col);
            uint2 d;
            d.x = cvtpk2(v.x, v.y);
            d.y = cvtpk2(v.z, v.w);
            *reinterpret_cast<uint2*>(As + swzT(row, col*2)) = d;
        }
        #pragma unroll
        for(int it=0; it<4; ++it){
            int idx = it*256 + tid;
            int row = idx >> 3;
            int colb = (idx & 7) * 16;
            uint4 vk = *reinterpret_cast<const uint4*>(BtK + (size_t)(n0+row)*512 + k0 + colb/2);
            uint4 vv = *reinterpret_cast<const uint4*>(BtV + (size_t)(n0+row)*512 + k0 + colb/2);
            *reinterpret_cast<uint4*>(BsK + swzT(row, colb)) = vk;
            *reinterpret_cast<uint4*>(BsV + swzT(row, colb)) = vv;
        }
        __syncthreads();
        #pragma unroll
        for(int kk=0; kk<2; ++kk){
            bf16x8 af[4];
            #pragma unroll
            for(int m=0;m<4;++m)
                af[m] = *reinterpret_cast<const bf16x8*>(As + swzT(wr*64 + m*16 + l15, kk*64 + lg*16));
            #pragma unroll
            for(int n=0;n<4;++n){
                bf16x8 bk = *reinterpret_cast<const bf16x8*>(BsK + swzT(wc*64 + n*16 + l15, kk*64 + lg*16));
                #pragma unroll
                for(int m=0;m<4;++m)
                    acck[m][n] = __builtin_amdgcn_mfma_f32_16x16x32_bf16(af[m], bk, acck[m][n], 0, 0, 0);
                bf16x8 bv = *reinterpret_cast<const bf16x8*>(BsV + swzT(wc*64 + n*16 + l15, kk*64 + lg*16));
                #pragma unroll
                for(int m=0;m<4;++m)
                    accv[m][n] = __builtin_amdgcn_mfma_f32_16x16x32_bf16(af[m], bv, accv[m][n], 0, 0, 0);
            }
        }
    }
    // K epilogue: row-major bf16
    #pragma unroll
    for(int m=0;m<4;++m){
        int row = m0 + wr*64 + m*16 + lg*4;
        #pragma unroll
        for(int n=0;n<4;++n){
            int col = n0 + wc*64 + n*16 + l15;
            float bv = bkv[col];
            #pragma unroll
            for(int j=0;j<4;++j)
                kp[(size_t)(row+j)*512 + col] = f2b(acck[m][n][j] + bv);
        }
    }
    // V epilogue: transposed per-head, 4 kpos packed per b64 store
    int z = m0 >> 10;
    #pragma unroll
    for(int m=0;m<4;++m){
        int kloc = (m0 & 1023) + wr*64 + m*16 + lg*4;
        #pragma unroll
        for(int n=0;n<4;++n){
            int col = n0 + wc*64 + n*16 + l15;   // h*64+d
            float bv = bvv[col];
            int vrow = (z*8 + (col >> 6))*64 + (col & 63);
            uint2 w;
            w.x = cvtpk2(accv[m][n][0] + bv, accv[m][n][1] + bv);
            w.y = cvtpk2(accv[m][n][2] + bv, accv[m][n][3] + bv);
            *reinterpret_cast<uint2*>(vpT + (size_t)vrow*1024 + kloc) = w;
        }
    }
}

// ---------------- GEMM: C[M][512] = A[M][512] @ W + bias --------------------
template<bool OUT_BF16, bool A_BF16>
__global__ __launch_bounds__(256) void gemm512(
    const void* __restrict__ Av,
    const unsigned short* __restrict__ Bt,
    const float* __restrict__ bias,
    void* __restrict__ Cv){
    __shared__ alignas(16) char sm[32768];
    char* As = sm;
    char* Bs = sm + 16384;
    int n0 = blockIdx.x * 128, m0 = blockIdx.y * 128;
    int tid = threadIdx.x;
    int l = tid & 63, wid = tid >> 6;
    int wr = wid >> 1, wc = wid & 1;
    int l15 = l & 15, lg = l >> 4;

    f32x4 acc[4][4];
    const f32x4 z4 = {0.f,0.f,0.f,0.f};
    #pragma unroll
    for(int m=0;m<4;++m)
        #pragma unroll
        for(int n=0;n<4;++n) acc[m][n] = z4;

    for(int kt=0; kt<8; ++kt){
        int k0 = kt*64;
        __syncthreads();
        if(A_BF16){
            const unsigned short* A = (const unsigned short*)Av;
            #pragma unroll
            for(int it=0; it<4; ++it){
                int idx = it*256 + tid;
                int row = idx >> 3;
                int colb = (idx & 7) * 16;
                uint4 v = *reinterpret_cast<const uint4*>(A + (size_t)(m0+row)*512 + k0 + colb/2);
                *reinterpret_cast<uint4*>(As + swzT(row, colb)) = v;
            }
        } else {
            const float* A = (const float*)Av;
            #pragma unroll
            for(int it=0; it<8; ++it){
                int idx = it*256 + tid;
                int row = idx >> 4;
                int col = (idx & 15) * 4;
                float4 v = *reinterpret_cast<const float4*>(A + (size_t)(m0+row)*512 + k0 + col);
                uint2 d;
                d.x = cvtpk2(v.x, v.y);
                d.y = cvtpk2(v.z, v.w);
                *reinterpret_cast<uint2*>(As + swzT(row, col*2)) = d;
            }
        }
        #pragma unroll
        for(int it=0; it<4; ++it){
            int idx = it*256 + tid;
            int row = idx >> 3;
            int colb = (idx & 7) * 16;
            uint4 v = *reinterpret_cast<const uint4*>(Bt + (size_t)(n0+row)*512 + k0 + colb/2);
            *reinterpret_cast<uint4*>(Bs + swzT(row, colb)) = v;
        }
        __syncthreads();
        #pragma unroll
        for(int kk=0; kk<2; ++kk){
            bf16x8 af[4], bfr[4];
            #pragma unroll
            for(int m=0;m<4;++m)
                af[m] = *reinterpret_cast<const bf16x8*>(As + swzT(wr*64 + m*16 + l15, kk*64 + lg*16));
            #pragma unroll
            for(int n=0;n<4;++n)
                bfr[n] = *reinterpret_cast<const bf16x8*>(Bs + swzT(wc*64 + n*16 + l15, kk*64 + lg*16));
            #pragma unroll
            for(int m=0;m<4;++m)
                #pragma unroll
                for(int n=0;n<4;++n)
                    acc[m][n] = __builtin_amdgcn_mfma_f32_16x16x32_bf16(af[m], bfr[n], acc[m][n], 0, 0, 0);
        }
    }
    #pragma unroll
    for(int m=0;m<4;++m){
        int row = m0 + wr*64 + m*16 + lg*4;
        #pragma unroll
        for(int n=0;n<4;++n){
            int col = n0 + wc*64 + n*16 + l15;
            float bv = bias[col];
            #pragma unroll
            for(int j=0;j<4;++j){
                float val = acc[m][n][j] + bv;
                if(OUT_BF16)
                    reinterpret_cast<unsigned short*>(Cv)[(size_t)(row+j)*512 + col] = f2b(val);
                else
                    reinterpret_cast<float*>(Cv)[(size_t)(row+j)*512 + col] = val;
            }
        }
    }
}

// ---------------- attention v3: 512 blocks x 4 waves, 32 q/wave -------------
__global__ __launch_bounds__(256) void attn3_kernel(
    const unsigned short* __restrict__ qp,   // [8192][512] bf16
    const unsigned short* __restrict__ kp,   // [32768][512] bf16
    const unsigned short* __restrict__ vpT,  // [(z*8+h)*64+d][1024] bf16
    const float* __restrict__ qwg,           // [1024][4] L2E-folded
    const float* __restrict__ kfg,           // [4096][4] L2E-folded
    unsigned short* __restrict__ ctxb){      // [8192][512] bf16
    __shared__ alignas(16) char sm[33792];
    char* Ks  = sm;            // [64 k][64 d] swizzled
    char* VTs = sm + 8192;     // [64 d][64 k] swizzled
    char* kfs = sm + 16384;    // [64 k][4 f32] linear
    char* Ps  = sm + 17408;    // per-wave 4096B: [32 q][64 k] swizzled

    const float SCALE2 = 0.18033688011112042f;   // 0.125 * log2(e)
    const float THR = 10.0f;

    int bid = blockIdx.x;
    int wg  = (bid & 7)*64 + (bid >> 3);         // XCD-chunked (512 = 8*64)
    int qs = wg & 1, h = (wg >> 1) & 7, z = wg >> 4;
    int b = z >> 3;
    int tid = threadIdx.x, l = tid & 63, wid = tid >> 6;
    int l15 = l & 15, lg = l >> 4;
    int srow = tid >> 3, sc8 = tid & 7;

    const unsigned short* kbase = kp  + (size_t)(z*1024)*512 + h*64;
    const unsigned short* vbase = vpT + (size_t)((z*8+h)*64)*1024;
    char* Pw = Ps + wid*4096;

    int qbase = z*256 + qs*128 + wid*32;

    // Q fragments: 2 q-subtiles x 2 d-halves
    bf16x8 qf[2][2];
    #pragma unroll
    for(int qh=0;qh<2;++qh)
        #pragma unroll
        for(int kk=0;kk<2;++kk)
            qf[qh][kk] = *reinterpret_cast<const bf16x8*>(
                qp + (size_t)(qbase + qh*16 + l15)*512 + h*64 + kk*32 + lg*8);

    // bias weights, paired for packed math: qwp[qh][pair][feat]
    f32x2 qwp[2][2][3];
    #pragma unroll
    for(int qh=0;qh<2;++qh){
        f32x4 qv[4];
        #pragma unroll
        for(int j=0;j<4;++j)
            qv[j] = *reinterpret_cast<const f32x4*>(
                qwg + (size_t)(b*256 + qs*128 + wid*32 + qh*16 + lg*4 + j)*4);
        #pragma unroll
        for(int p=0;p<2;++p)
            #pragma unroll
            for(int f=0;f<3;++f)
                qwp[qh][p][f] = (f32x2){qv[2*p][f], qv[2*p+1][f]};
    }

    float mrun[2][4];
    f32x2 psum[2][2];
    f32x4 acc[2][4];
    const f32x4 z4 = {0.f,0.f,0.f,0.f};
    #pragma unroll
    for(int qh=0;qh<2;++qh){
        #pragma unroll
        for(int j=0;j<4;++j) mrun[qh][j] = -3.0e38f;
        psum[qh][0] = (f32x2){0.f,0.f}; psum[qh][1] = (f32x2){0.f,0.f};
        #pragma unroll
        for(int t=0;t<4;++t) acc[qh][t] = z4;
    }

    // prefetch tile 0
    uint4 kreg[2], vreg[2], freg;
    #pragma unroll
    for(int it=0; it<2; ++it){
        int row = it*32 + srow;
        kreg[it] = *reinterpret_cast<const uint4*>(kbase + (size_t)row*512  + sc8*8);
        vreg[it] = *reinterpret_cast<const uint4*>(vbase + (size_t)row*1024 + sc8*8);
    }
    if(tid < 64) freg = *reinterpret_cast<const uint4*>(kfg + (size_t)(b*1024 + tid)*4);

    for(int kt=0; kt<16; ++kt){
        __syncthreads();
        #pragma unroll
        for(int it=0; it<2; ++it){
            int row = it*32 + srow;
            *reinterpret_cast<uint4*>(Ks  + swzT(row, sc8*16)) = kreg[it];
            *reinterpret_cast<uint4*>(VTs + swzT(row, sc8*16)) = vreg[it];
        }
        if(tid < 64) *reinterpret_cast<uint4*>(kfs + tid*16) = freg;
        __syncthreads();
        if(kt < 15){
            #pragma unroll
            for(int it=0; it<2; ++it){
                int row = it*32 + srow;
                kreg[it] = *reinterpret_cast<const uint4*>(kbase + (size_t)((kt+1)*64 + row)*512 + sc8*8);
                vreg[it] = *reinterpret_cast<const uint4*>(vbase + (size_t)row*1024 + (kt+1)*64 + sc8*8);
            }
            if(tid < 64) freg = *reinterpret_cast<const uint4*>(kfg + (size_t)(b*1024 + (kt+1)*64 + tid)*4);
        }

        // S = Q @ K^T for both q-subtiles
        f32x4 s[2][4];
        #pragma unroll
        for(int qh=0;qh<2;++qh)
            #pragma unroll
            for(int t=0;t<4;++t) s[qh][t] = z4;
        #pragma unroll
        for(int t=0;t<4;++t){
            #pragma unroll
            for(int kk=0;kk<2;++kk){
                bf16x8 kf = *reinterpret_cast<const bf16x8*>(Ks + swzT(t*16 + l15, kk*64 + lg*16));
                #pragma unroll
                for(int qh=0;qh<2;++qh)
                    s[qh][t] = __builtin_amdgcn_mfma_f32_16x16x32_bf16(qf[qh][kk], kf, s[qh][t], 0, 0, 0);
            }
        }
        // scale + rank-3 bias (packed f32 math)
        #pragma unroll
        for(int t=0;t<4;++t){
            f32x4 kv = *reinterpret_cast<const f32x4*>(kfs + (t*16 + l15)*16);
            f32x2 c0 = {kv[0],kv[0]}, c1 = {kv[1],kv[1]}, c2 = {kv[2],kv[2]}, c3 = {kv[3],kv[3]};
            #pragma unroll
            for(int qh=0;qh<2;++qh){
                f32x2 b01 = qwp[qh][0][0]*c0 + qwp[qh][0][1]*c1 + qwp[qh][0][2]*c2 + c3;
                f32x2 b23 = qwp[qh][1][0]*c0 + qwp[qh][1][1]*c1 + qwp[qh][1][2]*c2 + c3;
                f32x2 s01 = {s[qh][t][0], s[qh][t][1]};
                f32x2 s23 = {s[qh][t][2], s[qh][t][3]};
                s01 = s01*SCALE2 + b01;
                s23 = s23*SCALE2 + b23;
                s[qh][t][0] = s01.x; s[qh][t][1] = s01.y;
                s[qh][t][2] = s23.x; s[qh][t][3] = s23.y;
            }
        }
        // tile max per q-row (DPP butterfly, no LDS)
        float pm[2][4];
        bool need = false;
        #pragma unroll
        for(int qh=0;qh<2;++qh)
            #pragma unroll
            for(int j=0;j<4;++j){
                float mx = fmaxf(fmaxf(s[qh][0][j], s[qh][1][j]), fmaxf(s[qh][2][j], s[qh][3][j]));
                mx = grp16_max(mx);
                pm[qh][j] = mx;
                need = need || (mx > mrun[qh][j] + THR);
            }
        if(__any(need ? 1 : 0)){
            #pragma unroll
            for(int qh=0;qh<2;++qh)
                #pragma unroll
                for(int j=0;j<4;++j){
                    float mn = fmaxf(mrun[qh][j], pm[qh][j]);
                    float scl = exp2f(mrun[qh][j] - mn);
                    mrun[qh][j] = mn;
                    if(j<2){ if(j==0) psum[qh][0].x *= scl; else psum[qh][0].y *= scl; }
                    else   { if(j==2) psum[qh][1].x *= scl; else psum[qh][1].y *= scl; }
                    #pragma unroll
                    for(int t=0;t<4;++t) acc[qh][t][j] *= scl;
                }
        }
        // P = exp2(s - mrun), pack to bf16, per-wave LDS, per-lane partial sums
        #pragma unroll
        for(int qh=0;qh<2;++qh){
            int row0 = qh*16 + lg*4;
            #pragma unroll
            for(int t=0;t<4;++t){
                float p0 = exp2f(s[qh][t][0] - mrun[qh][0]);
                float p1 = exp2f(s[qh][t][1] - mrun[qh][1]);
                float p2 = exp2f(s[qh][t][2] - mrun[qh][2]);
                float p3 = exp2f(s[qh][t][3] - mrun[qh][3]);
                psum[qh][0] += (f32x2){p0, p1};
                psum[qh][1] += (f32x2){p2, p3};
                unsigned w01 = cvtpk2(p0, p1);
                unsigned w23 = cvtpk2(p2, p3);
                int cb = (t*16 + l15)*2;
                *reinterpret_cast<unsigned short*>(Pw + swzT(row0+0, cb)) = (unsigned short)w01;
                *reinterpret_cast<unsigned short*>(Pw + swzT(row0+1, cb)) = (unsigned short)(w01 >> 16);
                *reinterpret_cast<unsigned short*>(Pw + swzT(row0+2, cb)) = (unsigned short)w23;
                *reinterpret_cast<unsigned short*>(Pw + swzT(row0+3, cb)) = (unsigned short)(w23 >> 16);
            }
        }
        // PV (wave-local P; compiler orders ds_write->ds_read by alias)
        #pragma unroll
        for(int kk=0;kk<2;++kk){
            bf16x8 vf[4];
            #pragma unroll
            for(int t=0;t<4;++t)
                vf[t] = *reinterpret_cast<const bf16x8*>(VTs + swzT(t*16 + l15, kk*64 + lg*16));
            #pragma unroll
            for(int qh=0;qh<2;++qh){
                bf16x8 pa = *reinterpret_cast<const bf16x8*>(Pw + swzT(qh*16 + l15, kk*64 + lg*16));
                #pragma unroll
                for(int t=0;t<4;++t)
                    acc[qh][t] = __builtin_amdgcn_mfma_f32_16x16x32_bf16(pa, vf[t], acc[qh][t], 0, 0, 0);
            }
        }
    }
    // final row sums (one DPP butterfly), normalize, write bf16 ctx
    #pragma unroll
    for(int qh=0;qh<2;++qh){
        float rl[4];
        rl[0] = 1.0f / grp16_sum(psum[qh][0].x);
        rl[1] = 1.0f / grp16_sum(psum[qh][0].y);
        rl[2] = 1.0f / grp16_sum(psum[qh][1].x);
        rl[3] = 1.0f / grp16_sum(psum[qh][1].y);
        #pragma unroll
        for(int j=0;j<4;++j){
            int row = qbase + qh*16 + lg*4 + j;
            #pragma unroll
            for(int t=0;t<4;++t)
                ctxb[(size_t)row*512 + h*64 + t*16 + l15] = f2b(acc[qh][t][j] * rl[j]);
        }
    }
}

// ---------------------------------------------------------------------------
extern "C" void kernel_launch(void* const* d_in, const int* in_sizes, int n_in,
                              void* d_out, int out_size, void* d_ws, size_t ws_size,
                              hipStream_t stream){
    (void)in_sizes; (void)n_in; (void)out_size; (void)ws_size;
    const float* query     = (const float*)d_in[0];
    const float* key_value = (const float*)d_in[1];
    const float* query_pos = (const float*)d_in[2];
    const float* key_pos   = (const float*)d_in[3];
    const int*   key_mask  = (const int*)d_in[4];
    const float* Wq  = (const float*)d_in[5];
    const float* bq  = (const float*)d_in[6];
    const float* Wk  = (const float*)d_in[7];
    const float* bk  = (const float*)d_in[8];
    const float* Wv  = (const float*)d_in[9];
    const float* bv  = (const float*)d_in[10];
    const float* Wo  = (const float*)d_in[11];
    const float* bo  = (const float*)d_in[12];
    const float* Wqb = (const float*)d_in[13];
    const float* Wkb = (const float*)d_in[14];

    char* ws = (char*)d_ws;
    const size_t MB = 1048576;
    unsigned short* kp    = (unsigned short*)(ws);            // 32MB
    unsigned short* vpT   = (unsigned short*)(ws + 32*MB);    // 32MB
    unsigned short* qp    = (unsigned short*)(ws + 64*MB);    //  8MB
    unsigned short* ctxb  = (unsigned short*)(ws + 72*MB);    //  8MB
    unsigned short* WtQ   = (unsigned short*)(ws + 80*MB);    // 4 x 0.5MB
    unsigned short* WtK   = WtQ + 262144;
    unsigned short* WtV   = WtK + 262144;
    unsigned short* WtO   = WtV + 262144;
    float*          qwg   = (float*)(ws + 82*MB);             // 16KB
    float*          kfg   = (float*)(ws + 82*MB + 65536);     // 64KB

    wt4_kernel<<<dim3(8,8,4), 256, 0, stream>>>(Wq, Wk, Wv, Wo, WtQ);
    posfeat_kernel<<<20, 256, 0, stream>>>(query_pos, key_pos, Wqb, Wkb, key_mask, qwg, kfg);

    gemm_kv<<<dim3(4,256), 256, 0, stream>>>(key_value, WtK, WtV, bk, bv, kp, vpT);
    gemm512<true ,false><<<dim3(4,64), 256, 0, stream>>>(query, WtQ, bq, qp);

    attn3_kernel<<<512, 256, 0, stream>>>(qp, kp, vpT, qwg, kfg, ctxb);

    gemm512<false,true ><<<dim3(4,64), 256, 0, stream>>>(ctxb, WtO, bo, d_out);
}

// Round 5
// 218.084 us; speedup vs baseline: 1.0914x; 1.0914x over previous
//
#include <hip/hip_runtime.h>
#include <hip/hip_bf16.h>
#include <stdint.h>

// Shapes (fixed): B=4, N=8, Q=256, K=1024, D_MODEL=512, H=8, Dh=64, R=8, sigma=0.05

typedef __attribute__((ext_vector_type(8))) short bf16x8;
typedef __attribute__((ext_vector_type(4))) float f32x4;
typedef __attribute__((ext_vector_type(2))) float f32x2;

__device__ __forceinline__ unsigned short f2b(float f){
    unsigned int u = __builtin_bit_cast(unsigned int, f);
    unsigned int r = u + 0x7fffu + ((u >> 16) & 1u);   // RNE
    return (unsigned short)(r >> 16);
}

// packed f32->bf16x2 (RNE), single HW instr
__device__ __forceinline__ unsigned cvtpk2(float lo, float hi){
    unsigned r;
    asm("v_cvt_pk_bf16_f32 %0, %1, %2" : "=v"(r) : "v"(lo), "v"(hi));
    return r;
}

// single-level XOR swizzle (round-2 attn measured 0 conflicts with this)
__device__ __forceinline__ int swz(int row, int byteInRow){
    return row*128 + (byteInRow ^ ((row & 7) << 4));
}
// two-level swizzle used by the GEMMs
__device__ __forceinline__ int swzT(int row, int byteInRow){
    return row*128 + (byteInRow ^ (((row ^ (row >> 3)) & 7) << 4));
}

// DPP butterflies within 16-lane row: 0xB1=xor1, 0x4E=xor2, 0x141=half-mirror(xor7... ), 0x140=mirror
template<int CTRL>
__device__ __forceinline__ float dpp_mov(float x){
    return __builtin_bit_cast(float,
        __builtin_amdgcn_update_dpp(0, __builtin_bit_cast(int, x), CTRL, 0xF, 0xF, true));
}
__device__ __forceinline__ float grp16_max(float x){
    x = fmaxf(x, dpp_mov<0xB1>(x));
    x = fmaxf(x, dpp_mov<0x4E>(x));
    x = fmaxf(x, dpp_mov<0x141>(x));
    x = fmaxf(x, dpp_mov<0x140>(x));
    return x;
}
__device__ __forceinline__ float grp16_sum(float x){
    x += dpp_mov<0xB1>(x);
    x += dpp_mov<0x4E>(x);
    x += dpp_mov<0x141>(x);
    x += dpp_mov<0x140>(x);
    return x;
}

// ---------------- all 4 weight transposes in one launch ---------------------
__global__ __launch_bounds__(256) void wt4_kernel(
    const float* __restrict__ Wq, const float* __restrict__ Wk,
    const float* __restrict__ Wv, const float* __restrict__ Wo,
    unsigned short* __restrict__ WtBase){
    __shared__ float tile[64][65];
    int kt = blockIdx.x, nt = blockIdx.y, wsel = blockIdx.z;
    const float* W = (wsel == 0) ? Wq : (wsel == 1) ? Wk : (wsel == 2) ? Wv : Wo;
    unsigned short* Wt = WtBase + (size_t)wsel * 262144;
    int tid = threadIdx.x;
    #pragma unroll
    for(int it=0; it<16; ++it){
        int idx = it*256 + tid;
        int r = idx >> 6, c = idx & 63;
        tile[r][c] = W[(kt*64 + r)*512 + nt*64 + c];
    }
    __syncthreads();
    #pragma unroll
    for(int it=0; it<16; ++it){
        int idx = it*256 + tid;
        int r = idx >> 6, c = idx & 63;
        Wt[(nt*64 + r)*512 + kt*64 + c] = f2b(tile[c][r]);
    }
}

// ---------------- positional features (rank-3 collapsed bias) ---------------
__global__ __launch_bounds__(256) void posfeat_kernel(
    const float* __restrict__ qpos, const float* __restrict__ kpos,
    const float* __restrict__ Wqb,  const float* __restrict__ Wkb,
    const int* __restrict__ mask,
    float* __restrict__ qwg,        // [1024][4]
    float* __restrict__ kfg){       // [4096][4]
    const float L2E = 1.4426950408889634f;
    const float S8  = 0.35355339059327373f;
    int id = blockIdx.x*256 + threadIdx.x;
    if(id < 1024){
        const float* p = qpos + id*3;
        float x = p[0], y = p[1], z = p[2];
        float qw0 = 400.f*x, qw1 = 400.f*y, qw2 = 400.f*z;
        #pragma unroll
        for(int r=0;r<8;++r){
            float qb = x*Wqb[r] + y*Wqb[8+r] + z*Wqb[16+r];
            float c  = S8*qb;
            qw0 += c*Wkb[r];
            qw1 += c*Wkb[8+r];
            qw2 += c*Wkb[16+r];
        }
        float4 o = {L2E*qw0, L2E*qw1, L2E*qw2, 0.f};
        *reinterpret_cast<float4*>(qwg + (size_t)id*4) = o;
    } else if(id < 5120){
        int k = id - 1024;
        const float* p = kpos + k*3;
        float x = p[0], y = p[1], z = p[2];
        float n2 = -200.0f*(x*x + y*y + z*z)*L2E;
        int mk = mask[k];
        float4 o = {x, y, z, mk ? n2 : -3.0e38f};
        *reinterpret_cast<float4*>(kfg + (size_t)k*4) = o;
    }
}

// ---------------- fused K+V projection GEMM ---------------------------------
__global__ __launch_bounds__(256) void gemm_kv(
    const float* __restrict__ A,
    const unsigned short* __restrict__ BtK,
    const unsigned short* __restrict__ BtV,
    const float* __restrict__ bkv, const float* __restrict__ bvv,
    unsigned short* __restrict__ kp,
    unsigned short* __restrict__ vpT){
    __shared__ alignas(16) char sm[49152];
    char* As  = sm;
    char* BsK = sm + 16384;
    char* BsV = sm + 32768;
    int n0 = blockIdx.x * 128, m0 = blockIdx.y * 128;
    int tid = threadIdx.x;
    int l = tid & 63, wid = tid >> 6;
    int wr = wid >> 1, wc = wid & 1;
    int l15 = l & 15, lg = l >> 4;

    f32x4 acck[4][4], accv[4][4];
    const f32x4 z4 = {0.f,0.f,0.f,0.f};
    #pragma unroll
    for(int m=0;m<4;++m)
        #pragma unroll
        for(int n=0;n<4;++n){ acck[m][n] = z4; accv[m][n] = z4; }

    for(int kt=0; kt<8; ++kt){
        int k0 = kt*64;
        __syncthreads();
        #pragma unroll
        for(int it=0; it<8; ++it){
            int idx = it*256 + tid;
            int row = idx >> 4;
            int col = (idx & 15) * 4;
            float4 v = *reinterpret_cast<const float4*>(A + (size_t)(m0+row)*512 + k0 + col);
            uint2 d;
            d.x = cvtpk2(v.x, v.y);
            d.y = cvtpk2(v.z, v.w);
            *reinterpret_cast<uint2*>(As + swzT(row, col*2)) = d;
        }
        #pragma unroll
        for(int it=0; it<4; ++it){
            int idx = it*256 + tid;
            int row = idx >> 3;
            int colb = (idx & 7) * 16;
            uint4 vk = *reinterpret_cast<const uint4*>(BtK + (size_t)(n0+row)*512 + k0 + colb/2);
            uint4 vv = *reinterpret_cast<const uint4*>(BtV + (size_t)(n0+row)*512 + k0 + colb/2);
            *reinterpret_cast<uint4*>(BsK + swzT(row, colb)) = vk;
            *reinterpret_cast<uint4*>(BsV + swzT(row, colb)) = vv;
        }
        __syncthreads();
        #pragma unroll
        for(int kk=0; kk<2; ++kk){
            bf16x8 af[4];
            #pragma unroll
            for(int m=0;m<4;++m)
                af[m] = *reinterpret_cast<const bf16x8*>(As + swzT(wr*64 + m*16 + l15, kk*64 + lg*16));
            #pragma unroll
            for(int n=0;n<4;++n){
                bf16x8 bk = *reinterpret_cast<const bf16x8*>(BsK + swzT(wc*64 + n*16 + l15, kk*64 + lg*16));
                #pragma unroll
                for(int m=0;m<4;++m)
                    acck[m][n] = __builtin_amdgcn_mfma_f32_16x16x32_bf16(af[m], bk, acck[m][n], 0, 0, 0);
                bf16x8 bv = *reinterpret_cast<const bf16x8*>(BsV + swzT(wc*64 + n*16 + l15, kk*64 + lg*16));
                #pragma unroll
                for(int m=0;m<4;++m)
                    accv[m][n] = __builtin_amdgcn_mfma_f32_16x16x32_bf16(af[m], bv, accv[m][n], 0, 0, 0);
            }
        }
    }
    #pragma unroll
    for(int m=0;m<4;++m){
        int row = m0 + wr*64 + m*16 + lg*4;
        #pragma unroll
        for(int n=0;n<4;++n){
            int col = n0 + wc*64 + n*16 + l15;
            float bv = bkv[col];
            #pragma unroll
            for(int j=0;j<4;++j)
                kp[(size_t)(row+j)*512 + col] = f2b(acck[m][n][j] + bv);
        }
    }
    int z = m0 >> 10;
    #pragma unroll
    for(int m=0;m<4;++m){
        int kloc = (m0 & 1023) + wr*64 + m*16 + lg*4;
        #pragma unroll
        for(int n=0;n<4;++n){
            int col = n0 + wc*64 + n*16 + l15;   // h*64+d
            float bv = bvv[col];
            int vrow = (z*8 + (col >> 6))*64 + (col & 63);
            uint2 w;
            w.x = cvtpk2(accv[m][n][0] + bv, accv[m][n][1] + bv);
            w.y = cvtpk2(accv[m][n][2] + bv, accv[m][n][3] + bv);
            *reinterpret_cast<uint2*>(vpT + (size_t)vrow*1024 + kloc) = w;
        }
    }
}

// ---------------- GEMM: C[M][512] = A[M][512] @ W + bias --------------------
template<bool OUT_BF16, bool A_BF16>
__global__ __launch_bounds__(256) void gemm512(
    const void* __restrict__ Av,
    const unsigned short* __restrict__ Bt,
    const float* __restrict__ bias,
    void* __restrict__ Cv){
    __shared__ alignas(16) char sm[32768];
    char* As = sm;
    char* Bs = sm + 16384;
    int n0 = blockIdx.x * 128, m0 = blockIdx.y * 128;
    int tid = threadIdx.x;
    int l = tid & 63, wid = tid >> 6;
    int wr = wid >> 1, wc = wid & 1;
    int l15 = l & 15, lg = l >> 4;

    f32x4 acc[4][4];
    const f32x4 z4 = {0.f,0.f,0.f,0.f};
    #pragma unroll
    for(int m=0;m<4;++m)
        #pragma unroll
        for(int n=0;n<4;++n) acc[m][n] = z4;

    for(int kt=0; kt<8; ++kt){
        int k0 = kt*64;
        __syncthreads();
        if(A_BF16){
            const unsigned short* A = (const unsigned short*)Av;
            #pragma unroll
            for(int it=0; it<4; ++it){
                int idx = it*256 + tid;
                int row = idx >> 3;
                int colb = (idx & 7) * 16;
                uint4 v = *reinterpret_cast<const uint4*>(A + (size_t)(m0+row)*512 + k0 + colb/2);
                *reinterpret_cast<uint4*>(As + swzT(row, colb)) = v;
            }
        } else {
            const float* A = (const float*)Av;
            #pragma unroll
            for(int it=0; it<8; ++it){
                int idx = it*256 + tid;
                int row = idx >> 4;
                int col = (idx & 15) * 4;
                float4 v = *reinterpret_cast<const float4*>(A + (size_t)(m0+row)*512 + k0 + col);
                uint2 d;
                d.x = cvtpk2(v.x, v.y);
                d.y = cvtpk2(v.z, v.w);
                *reinterpret_cast<uint2*>(As + swzT(row, col*2)) = d;
            }
        }
        #pragma unroll
        for(int it=0; it<4; ++it){
            int idx = it*256 + tid;
            int row = idx >> 3;
            int colb = (idx & 7) * 16;
            uint4 v = *reinterpret_cast<const uint4*>(Bt + (size_t)(n0+row)*512 + k0 + colb/2);
            *reinterpret_cast<uint4*>(Bs + swzT(row, colb)) = v;
        }
        __syncthreads();
        #pragma unroll
        for(int kk=0; kk<2; ++kk){
            bf16x8 af[4], bfr[4];
            #pragma unroll
            for(int m=0;m<4;++m)
                af[m] = *reinterpret_cast<const bf16x8*>(As + swzT(wr*64 + m*16 + l15, kk*64 + lg*16));
            #pragma unroll
            for(int n=0;n<4;++n)
                bfr[n] = *reinterpret_cast<const bf16x8*>(Bs + swzT(wc*64 + n*16 + l15, kk*64 + lg*16));
            #pragma unroll
            for(int m=0;m<4;++m)
                #pragma unroll
                for(int n=0;n<4;++n)
                    acc[m][n] = __builtin_amdgcn_mfma_f32_16x16x32_bf16(af[m], bfr[n], acc[m][n], 0, 0, 0);
        }
    }
    #pragma unroll
    for(int m=0;m<4;++m){
        int row = m0 + wr*64 + m*16 + lg*4;
        #pragma unroll
        for(int n=0;n<4;++n){
            int col = n0 + wc*64 + n*16 + l15;
            float bv = bias[col];
            #pragma unroll
            for(int j=0;j<4;++j){
                float val = acc[m][n][j] + bv;
                if(OUT_BF16)
                    reinterpret_cast<unsigned short*>(Cv)[(size_t)(row+j)*512 + col] = f2b(val);
                else
                    reinterpret_cast<float*>(Cv)[(size_t)(row+j)*512 + col] = val;
            }
        }
    }
}

// ---------------- attention v4: barrier-free, fragments direct from L2 ------
// 512 blocks x 256 threads (4 waves); wave = 32 q-rows; block = (z,h,q-half).
// K (kp) and V^T (vpT) global layouts ARE the fragment layouts: each 16B lane
// load lands in a fully-consumed 64B line (16 rows x 64B per instruction).
// No LDS staging, no __syncthreads anywhere. P round-trips per-wave LDS (swz).
__global__ __launch_bounds__(256) void attn4_kernel(
    const unsigned short* __restrict__ qp,   // [8192][512] bf16
    const unsigned short* __restrict__ kp,   // [32768][512] bf16
    const unsigned short* __restrict__ vpT,  // [(z*8+h)*64+d][1024] bf16
    const float* __restrict__ qwg,           // [1024][4] L2E-folded
    const float* __restrict__ kfg,           // [4096][4] L2E-folded
    unsigned short* __restrict__ ctxb){      // [8192][512] bf16
    __shared__ alignas(16) char Ps[16384];   // 4 waves x 4096B: [32 q][64 k] swz

    const float SCALE2 = 0.18033688011112042f;   // 0.125 * log2(e)
    const float THR = 10.0f;

    // decode so the two q-half blocks of one (z,h) land on the SAME XCD
    int bid = blockIdx.x;
    int xcd = bid & 7, idx = bid >> 3;
    int zh = xcd*32 + (idx >> 1), qs = idx & 1;
    int z = zh >> 3, h = zh & 7;
    int b = z >> 3;
    int tid = threadIdx.x, l = tid & 63, wid = tid >> 6;
    int l15 = l & 15, lg = l >> 4;

    const unsigned short* kbase = kp  + (size_t)(z*1024)*512 + h*64;
    const unsigned short* vbase = vpT + (size_t)((z*8+h)*64)*1024;
    const float* kfb = kfg + (size_t)(b*1024)*4;
    char* Pw = Ps + wid*4096;
    int qbase = z*256 + qs*128 + wid*32;

    // Q fragments: 2 q-subtiles x 2 d-halves (held in regs for all 16 tiles)
    bf16x8 qf[2][2];
    #pragma unroll
    for(int qh=0;qh<2;++qh)
        #pragma unroll
        for(int kk=0;kk<2;++kk)
            qf[qh][kk] = *reinterpret_cast<const bf16x8*>(
                qp + (size_t)(qbase + qh*16 + l15)*512 + h*64 + kk*32 + lg*8);

    // bias weights, paired for packed math
    f32x2 qwp[2][2][3];
    #pragma unroll
    for(int qh=0;qh<2;++qh){
        f32x4 qv[4];
        #pragma unroll
        for(int j=0;j<4;++j)
            qv[j] = *reinterpret_cast<const f32x4*>(
                qwg + (size_t)(b*256 + qs*128 + wid*32 + qh*16 + lg*4 + j)*4);
        #pragma unroll
        for(int p=0;p<2;++p)
            #pragma unroll
            for(int f=0;f<3;++f)
                qwp[qh][p][f] = (f32x2){qv[2*p][f], qv[2*p+1][f]};
    }

    float mrun[2][4];
    f32x2 psum[2][2];
    f32x4 acc[2][4];
    const f32x4 z4 = {0.f,0.f,0.f,0.f};
    #pragma unroll
    for(int qh=0;qh<2;++qh){
        #pragma unroll
        for(int j=0;j<4;++j) mrun[qh][j] = -3.0e38f;
        psum[qh][0] = (f32x2){0.f,0.f}; psum[qh][1] = (f32x2){0.f,0.f};
        #pragma unroll
        for(int t=0;t<4;++t) acc[qh][t] = z4;
    }

    for(int kt=0; kt<16; ++kt){
        const unsigned short* ktk = kbase + (size_t)(kt*64)*512;
        // K fragments + bias features direct from global (L2-resident)
        bf16x8 kf[4][2];
        #pragma unroll
        for(int t=0;t<4;++t)
            #pragma unroll
            for(int kk=0;kk<2;++kk)
                kf[t][kk] = *reinterpret_cast<const bf16x8*>(
                    ktk + (size_t)(t*16 + l15)*512 + kk*32 + lg*8);
        f32x4 kv[4];
        #pragma unroll
        for(int t=0;t<4;++t)
            kv[t] = *reinterpret_cast<const f32x4*>(kfb + (size_t)(kt*64 + t*16 + l15)*4);

        // S = Q @ K^T
        f32x4 s[2][4];
        #pragma unroll
        for(int qh=0;qh<2;++qh)
            #pragma unroll
            for(int t=0;t<4;++t) s[qh][t] = z4;
        #pragma unroll
        for(int t=0;t<4;++t)
            #pragma unroll
            for(int kk=0;kk<2;++kk)
                #pragma unroll
                for(int qh=0;qh<2;++qh)
                    s[qh][t] = __builtin_amdgcn_mfma_f32_16x16x32_bf16(qf[qh][kk], kf[t][kk], s[qh][t], 0, 0, 0);

        // V fragments issued early so their latency hides under softmax VALU
        bf16x8 vf[4][2];
        #pragma unroll
        for(int t=0;t<4;++t)
            #pragma unroll
            for(int kk=0;kk<2;++kk)
                vf[t][kk] = *reinterpret_cast<const bf16x8*>(
                    vbase + (size_t)(t*16 + l15)*1024 + kt*64 + kk*32 + lg*8);

        // scale + rank-3 bias (packed f32 math); mask folded into kv[3]
        #pragma unroll
        for(int t=0;t<4;++t){
            f32x2 c0 = {kv[t][0],kv[t][0]}, c1 = {kv[t][1],kv[t][1]},
                  c2 = {kv[t][2],kv[t][2]}, c3 = {kv[t][3],kv[t][3]};
            #pragma unroll
            for(int qh=0;qh<2;++qh){
                f32x2 b01 = qwp[qh][0][0]*c0 + qwp[qh][0][1]*c1 + qwp[qh][0][2]*c2 + c3;
                f32x2 b23 = qwp[qh][1][0]*c0 + qwp[qh][1][1]*c1 + qwp[qh][1][2]*c2 + c3;
                f32x2 s01 = {s[qh][t][0], s[qh][t][1]};
                f32x2 s23 = {s[qh][t][2], s[qh][t][3]};
                s01 = s01*SCALE2 + b01;
                s23 = s23*SCALE2 + b23;
                s[qh][t][0] = s01.x; s[qh][t][1] = s01.y;
                s[qh][t][2] = s23.x; s[qh][t][3] = s23.y;
            }
        }
        // tile max per q-row (DPP butterfly)
        float pm[2][4];
        bool need = false;
        #pragma unroll
        for(int qh=0;qh<2;++qh)
            #pragma unroll
            for(int j=0;j<4;++j){
                float mx = fmaxf(fmaxf(s[qh][0][j], s[qh][1][j]), fmaxf(s[qh][2][j], s[qh][3][j]));
                mx = grp16_max(mx);
                pm[qh][j] = mx;
                need = need || (mx > mrun[qh][j] + THR);
            }
        if(__any(need ? 1 : 0)){
            #pragma unroll
            for(int qh=0;qh<2;++qh)
                #pragma unroll
                for(int j=0;j<4;++j){
                    float mn = fmaxf(mrun[qh][j], pm[qh][j]);
                    float scl = exp2f(mrun[qh][j] - mn);
                    mrun[qh][j] = mn;
                    if(j<2){ if(j==0) psum[qh][0].x *= scl; else psum[qh][0].y *= scl; }
                    else   { if(j==2) psum[qh][1].x *= scl; else psum[qh][1].y *= scl; }
                    #pragma unroll
                    for(int t=0;t<4;++t) acc[qh][t][j] *= scl;
                }
        }
        // P = exp2(s - mrun): psum in-lane, pack bf16, scatter to per-wave LDS
        #pragma unroll
        for(int qh=0;qh<2;++qh){
            int row0 = qh*16 + lg*4;
            #pragma unroll
            for(int t=0;t<4;++t){
                float p0 = exp2f(s[qh][t][0] - mrun[qh][0]);
                float p1 = exp2f(s[qh][t][1] - mrun[qh][1]);
                float p2 = exp2f(s[qh][t][2] - mrun[qh][2]);
                float p3 = exp2f(s[qh][t][3] - mrun[qh][3]);
                psum[qh][0] += (f32x2){p0, p1};
                psum[qh][1] += (f32x2){p2, p3};
                unsigned w01 = cvtpk2(p0, p1);
                unsigned w23 = cvtpk2(p2, p3);
                int cb = (t*16 + l15)*2;
                *reinterpret_cast<unsigned short*>(Pw + swz(row0+0, cb)) = (unsigned short)w01;
                *reinterpret_cast<unsigned short*>(Pw + swz(row0+1, cb)) = (unsigned short)(w01 >> 16);
                *reinterpret_cast<unsigned short*>(Pw + swz(row0+2, cb)) = (unsigned short)w23;
                *reinterpret_cast<unsigned short*>(Pw + swz(row0+3, cb)) = (unsigned short)(w23 >> 16);
            }
        }
        // PV (P wave-local; compiler orders ds_write->ds_read)
        #pragma unroll
        for(int kk=0;kk<2;++kk){
            #pragma unroll
            for(int qh=0;qh<2;++qh){
                bf16x8 pa = *reinterpret_cast<const bf16x8*>(Pw + swz(qh*16 + l15, kk*64 + lg*16));
                #pragma unroll
                for(int t=0;t<4;++t)
                    acc[qh][t] = __builtin_amdgcn_mfma_f32_16x16x32_bf16(pa, vf[t][kk], acc[qh][t], 0, 0, 0);
            }
        }
    }
    // final row sums (one DPP butterfly), normalize, write bf16 ctx
    #pragma unroll
    for(int qh=0;qh<2;++qh){
        float rl[4];
        rl[0] = 1.0f / grp16_sum(psum[qh][0].x);
        rl[1] = 1.0f / grp16_sum(psum[qh][0].y);
        rl[2] = 1.0f / grp16_sum(psum[qh][1].x);
        rl[3] = 1.0f / grp16_sum(psum[qh][1].y);
        #pragma unroll
        for(int j=0;j<4;++j){
            int row = qbase + qh*16 + lg*4 + j;
            #pragma unroll
            for(int t=0;t<4;++t)
                ctxb[(size_t)row*512 + h*64 + t*16 + l15] = f2b(acc[qh][t][j] * rl[j]);
        }
    }
}

// ---------------------------------------------------------------------------
extern "C" void kernel_launch(void* const* d_in, const int* in_sizes, int n_in,
                              void* d_out, int out_size, void* d_ws, size_t ws_size,
                              hipStream_t stream){
    (void)in_sizes; (void)n_in; (void)out_size; (void)ws_size;
    const float* query     = (const float*)d_in[0];
    const float* key_value = (const float*)d_in[1];
    const float* query_pos = (const float*)d_in[2];
    const float* key_pos   = (const float*)d_in[3];
    const int*   key_mask  = (const int*)d_in[4];
    const float* Wq  = (const float*)d_in[5];
    const float* bq  = (const float*)d_in[6];
    const float* Wk  = (const float*)d_in[7];
    const float* bk  = (const float*)d_in[8];
    const float* Wv  = (const float*)d_in[9];
    const float* bv  = (const float*)d_in[10];
    const float* Wo  = (const float*)d_in[11];
    const float* bo  = (const float*)d_in[12];
    const float* Wqb = (const float*)d_in[13];
    const float* Wkb = (const float*)d_in[14];

    char* ws = (char*)d_ws;
    const size_t MB = 1048576;
    unsigned short* kp    = (unsigned short*)(ws);            // 32MB
    unsigned short* vpT   = (unsigned short*)(ws + 32*MB);    // 32MB
    unsigned short* qp    = (unsigned short*)(ws + 64*MB);    //  8MB
    unsigned short* ctxb  = (unsigned short*)(ws + 72*MB);    //  8MB
    unsigned short* WtQ   = (unsigned short*)(ws + 80*MB);    // 4 x 0.5MB
    unsigned short* WtK   = WtQ + 262144;
    unsigned short* WtV   = WtK + 262144;
    unsigned short* WtO   = WtV + 262144;
    float*          qwg   = (float*)(ws + 82*MB);             // 16KB
    float*          kfg   = (float*)(ws + 82*MB + 65536);     // 64KB

    wt4_kernel<<<dim3(8,8,4), 256, 0, stream>>>(Wq, Wk, Wv, Wo, WtQ);
    posfeat_kernel<<<20, 256, 0, stream>>>(query_pos, key_pos, Wqb, Wkb, key_mask, qwg, kfg);

    gemm_kv<<<dim3(4,256), 256, 0, stream>>>(key_value, WtK, WtV, bk, bv, kp, vpT);
    gemm512<true ,false><<<dim3(4,64), 256, 0, stream>>>(query, WtQ, bq, qp);

    attn4_kernel<<<512, 256, 0, stream>>>(qp, kp, vpT, qwg, kfg, ctxb);

    gemm512<false,true ><<<dim3(4,64), 256, 0, stream>>>(ctxb, WtO, bo, d_out);
}

// Round 6
// 197.214 us; speedup vs baseline: 1.2069x; 1.1058x over previous
//
#include <hip/hip_runtime.h>
#include <hip/hip_bf16.h>
#include <stdint.h>

// Shapes (fixed): B=4, N=8, Q=256, K=1024, D_MODEL=512, H=8, Dh=64, R=8, sigma=0.05

typedef __attribute__((ext_vector_type(8))) short bf16x8;
typedef __attribute__((ext_vector_type(4))) float f32x4;
typedef __attribute__((ext_vector_type(2))) float f32x2;

__device__ __forceinline__ unsigned short f2b(float f){
    unsigned int u = __builtin_bit_cast(unsigned int, f);
    unsigned int r = u + 0x7fffu + ((u >> 16) & 1u);   // RNE
    return (unsigned short)(r >> 16);
}

// packed f32->bf16x2 (RNE), single HW instr
__device__ __forceinline__ unsigned cvtpk2(float lo, float hi){
    unsigned r;
    asm("v_cvt_pk_bf16_f32 %0, %1, %2" : "=v"(r) : "v"(lo), "v"(hi));
    return r;
}

// single-level XOR swizzle for 64-col bf16 LDS tiles (0 conflicts measured r2)
__device__ __forceinline__ int swz(int row, int byteInRow){
    return row*128 + (byteInRow ^ ((row & 7) << 4));
}

// direct-to-LDS async copy, 16B per lane; LDS dest is wave-uniform base + lane*16
#define GLDS16(g, l) __builtin_amdgcn_global_load_lds( \
    (const __attribute__((address_space(1))) void*)(g), \
    (__attribute__((address_space(3))) void*)(l), 16, 0, 0)

// DPP butterflies within 16-lane row
template<int CTRL>
__device__ __forceinline__ float dpp_mov(float x){
    return __builtin_bit_cast(float,
        __builtin_amdgcn_update_dpp(0, __builtin_bit_cast(int, x), CTRL, 0xF, 0xF, true));
}
__device__ __forceinline__ float grp16_max(float x){
    x = fmaxf(x, dpp_mov<0xB1>(x));
    x = fmaxf(x, dpp_mov<0x4E>(x));
    x = fmaxf(x, dpp_mov<0x141>(x));
    x = fmaxf(x, dpp_mov<0x140>(x));
    return x;
}
__device__ __forceinline__ float grp16_sum(float x){
    x += dpp_mov<0xB1>(x);
    x += dpp_mov<0x4E>(x);
    x += dpp_mov<0x141>(x);
    x += dpp_mov<0x140>(x);
    return x;
}

// ---------------- all 4 weight transposes in one launch ---------------------
__global__ __launch_bounds__(256) void wt4_kernel(
    const float* __restrict__ Wq, const float* __restrict__ Wk,
    const float* __restrict__ Wv, const float* __restrict__ Wo,
    unsigned short* __restrict__ WtBase){
    __shared__ float tile[64][65];
    int kt = blockIdx.x, nt = blockIdx.y, wsel = blockIdx.z;
    const float* W = (wsel == 0) ? Wq : (wsel == 1) ? Wk : (wsel == 2) ? Wv : Wo;
    unsigned short* Wt = WtBase + (size_t)wsel * 262144;
    int tid = threadIdx.x;
    #pragma unroll
    for(int it=0; it<16; ++it){
        int idx = it*256 + tid;
        int r = idx >> 6, c = idx & 63;
        tile[r][c] = W[(kt*64 + r)*512 + nt*64 + c];
    }
    __syncthreads();
    #pragma unroll
    for(int it=0; it<16; ++it){
        int idx = it*256 + tid;
        int r = idx >> 6, c = idx & 63;
        Wt[(nt*64 + r)*512 + kt*64 + c] = f2b(tile[c][r]);
    }
}

// ---------------- positional features (rank-3 collapsed bias) ---------------
__global__ __launch_bounds__(256) void posfeat_kernel(
    const float* __restrict__ qpos, const float* __restrict__ kpos,
    const float* __restrict__ Wqb,  const float* __restrict__ Wkb,
    const int* __restrict__ mask,
    float* __restrict__ qwg,        // [1024][4]
    float* __restrict__ kfg){       // [4096][4]
    const float L2E = 1.4426950408889634f;
    const float S8  = 0.35355339059327373f;
    int id = blockIdx.x*256 + threadIdx.x;
    if(id < 1024){
        const float* p = qpos + id*3;
        float x = p[0], y = p[1], z = p[2];
        float qw0 = 400.f*x, qw1 = 400.f*y, qw2 = 400.f*z;
        #pragma unroll
        for(int r=0;r<8;++r){
            float qb = x*Wqb[r] + y*Wqb[8+r] + z*Wqb[16+r];
            float c  = S8*qb;
            qw0 += c*Wkb[r];
            qw1 += c*Wkb[8+r];
            qw2 += c*Wkb[16+r];
        }
        float4 o = {L2E*qw0, L2E*qw1, L2E*qw2, 0.f};
        *reinterpret_cast<float4*>(qwg + (size_t)id*4) = o;
    } else if(id < 5120){
        int k = id - 1024;
        const float* p = kpos + k*3;
        float x = p[0], y = p[1], z = p[2];
        float n2 = -200.0f*(x*x + y*y + z*z)*L2E;
        int mk = mask[k];
        float4 o = {x, y, z, mk ? n2 : -3.0e38f};
        *reinterpret_cast<float4*>(kfg + (size_t)k*4) = o;
    }
}

// ---------------- f32 -> bf16 streaming convert (8 elems/thread) ------------
__global__ __launch_bounds__(256) void cvt_kernel(
    const float* __restrict__ in, unsigned short* __restrict__ out, int n8){
    for(int id = blockIdx.x*256 + threadIdx.x; id < n8; id += gridDim.x*256){
        const float4* ip = reinterpret_cast<const float4*>(in) + (size_t)id*2;
        float4 a = ip[0], b = ip[1];
        uint4 w;
        w.x = cvtpk2(a.x, a.y); w.y = cvtpk2(a.z, a.w);
        w.z = cvtpk2(b.x, b.y); w.w = cvtpk2(b.z, b.w);
        reinterpret_cast<uint4*>(out)[id] = w;
    }
}

// ---------------- GEMM (m97 structure): A bf16 [M][512] @ Bt bf16 -----------
// 128x128 tile, BK=64, global_load_lds(16B) staging with pre-swizzled source,
// swizzled ds_read_b128 fragments. EPI: 0=bf16 row-major, 1=f32 row-major,
// 2=bf16 transposed per-head (vpT).
template<int EPI>
__global__ __launch_bounds__(256, 4) void gemm512g(
    const unsigned short* __restrict__ A,
    const unsigned short* __restrict__ Bt,
    const float* __restrict__ bias,
    void* __restrict__ Cv){
    __shared__ alignas(16) char sm[32768];
    char* As = sm;
    char* Bs = sm + 16384;

    int nwg = gridDim.x;                     // divisible by 8
    int q8  = nwg >> 3;
    int bid = blockIdx.x;
    int wgid = (bid & 7)*q8 + (bid >> 3);    // XCD-chunked bijection
    int n0 = (wgid & 3)*128, m0 = (wgid >> 2)*128;

    int tid = threadIdx.x;
    int l = tid & 63, wid = tid >> 6;
    int wr = wid >> 1, wc = wid & 1;
    int l15 = l & 15, lg = l >> 4;

    // glds source pre-swizzle: lane l covers (row = 8i+ (l>>3), swz-col (l&7)*16)
    // source byte col = ((l&7) ^ (l>>3)) * 16   (involution of swz)
    int srow8 = l >> 3;
    int scolb = ((l & 7) ^ srow8) << 4;

    f32x4 acc[4][4];
    const f32x4 z4 = {0.f,0.f,0.f,0.f};
    #pragma unroll
    for(int m=0;m<4;++m)
        #pragma unroll
        for(int n=0;n<4;++n) acc[m][n] = z4;

    for(int kt=0; kt<8; ++kt){
        int k0 = kt*64;
        __syncthreads();
        #pragma unroll
        for(int i=0;i<4;++i){
            int row = wid*32 + i*8 + srow8;
            const char* asrc = (const char*)(A  + (size_t)(m0+row)*512 + k0) + scolb;
            const char* bsrc = (const char*)(Bt + (size_t)(n0+row)*512 + k0) + scolb;
            GLDS16(asrc, As + wid*4096 + i*1024);
            GLDS16(bsrc, Bs + wid*4096 + i*1024);
        }
        __syncthreads();
        #pragma unroll
        for(int kk=0; kk<2; ++kk){
            bf16x8 af[4], bfr[4];
            #pragma unroll
            for(int m=0;m<4;++m)
                af[m] = *reinterpret_cast<const bf16x8*>(As + swz(wr*64 + m*16 + l15, kk*64 + lg*16));
            #pragma unroll
            for(int n=0;n<4;++n)
                bfr[n] = *reinterpret_cast<const bf16x8*>(Bs + swz(wc*64 + n*16 + l15, kk*64 + lg*16));
            #pragma unroll
            for(int m=0;m<4;++m)
                #pragma unroll
                for(int n=0;n<4;++n)
                    acc[m][n] = __builtin_amdgcn_mfma_f32_16x16x32_bf16(af[m], bfr[n], acc[m][n], 0, 0, 0);
        }
    }

    if(EPI == 2){
        // V: transposed per-head. local z-slice = m0>>10 (chunk-local), caller
        // offsets the output pointer per chunk.
        unsigned short* vpT = (unsigned short*)Cv;
        int z = m0 >> 10;
        #pragma unroll
        for(int m=0;m<4;++m){
            int kloc = (m0 & 1023) + wr*64 + m*16 + lg*4;
            #pragma unroll
            for(int n=0;n<4;++n){
                int col = n0 + wc*64 + n*16 + l15;   // h*64+d
                float bv = bias[col];
                int vrow = (z*8 + (col >> 6))*64 + (col & 63);
                uint2 w;
                w.x = cvtpk2(acc[m][n][0] + bv, acc[m][n][1] + bv);
                w.y = cvtpk2(acc[m][n][2] + bv, acc[m][n][3] + bv);
                *reinterpret_cast<uint2*>(vpT + (size_t)vrow*1024 + kloc) = w;
            }
        }
    } else {
        #pragma unroll
        for(int m=0;m<4;++m){
            int row = m0 + wr*64 + m*16 + lg*4;
            #pragma unroll
            for(int n=0;n<4;++n){
                int col = n0 + wc*64 + n*16 + l15;
                float bv = bias[col];
                #pragma unroll
                for(int j=0;j<4;++j){
                    float val = acc[m][n][j] + bv;
                    if(EPI == 0)
                        reinterpret_cast<unsigned short*>(Cv)[(size_t)(row+j)*512 + col] = f2b(val);
                    else
                        reinterpret_cast<float*>(Cv)[(size_t)(row+j)*512 + col] = val;
                }
            }
        }
    }
}

// ---------------- attention v4: barrier-free, fragments direct from L2 ------
__global__ __launch_bounds__(256) void attn4_kernel(
    const unsigned short* __restrict__ qp,   // [8192][512] bf16
    const unsigned short* __restrict__ kp,   // [32768][512] bf16
    const unsigned short* __restrict__ vpT,  // [(z*8+h)*64+d][1024] bf16
    const float* __restrict__ qwg,           // [1024][4] L2E-folded
    const float* __restrict__ kfg,           // [4096][4] L2E-folded
    unsigned short* __restrict__ ctxb){      // [8192][512] bf16
    __shared__ alignas(16) char Ps[16384];   // 4 waves x 4096B: [32 q][64 k] swz

    const float SCALE2 = 0.18033688011112042f;   // 0.125 * log2(e)
    const float THR = 10.0f;

    int bid = blockIdx.x;
    int xcd = bid & 7, idx = bid >> 3;
    int zh = xcd*32 + (idx >> 1), qs = idx & 1;
    int z = zh >> 3, h = zh & 7;
    int b = z >> 3;
    int tid = threadIdx.x, l = tid & 63, wid = tid >> 6;
    int l15 = l & 15, lg = l >> 4;

    const unsigned short* kbase = kp  + (size_t)(z*1024)*512 + h*64;
    const unsigned short* vbase = vpT + (size_t)((z*8+h)*64)*1024;
    const float* kfb = kfg + (size_t)(b*1024)*4;
    char* Pw = Ps + wid*4096;
    int qbase = z*256 + qs*128 + wid*32;

    bf16x8 qf[2][2];
    #pragma unroll
    for(int qh=0;qh<2;++qh)
        #pragma unroll
        for(int kk=0;kk<2;++kk)
            qf[qh][kk] = *reinterpret_cast<const bf16x8*>(
                qp + (size_t)(qbase + qh*16 + l15)*512 + h*64 + kk*32 + lg*8);

    f32x2 qwp[2][2][3];
    #pragma unroll
    for(int qh=0;qh<2;++qh){
        f32x4 qv[4];
        #pragma unroll
        for(int j=0;j<4;++j)
            qv[j] = *reinterpret_cast<const f32x4*>(
                qwg + (size_t)(b*256 + qs*128 + wid*32 + qh*16 + lg*4 + j)*4);
        #pragma unroll
        for(int p=0;p<2;++p)
            #pragma unroll
            for(int f=0;f<3;++f)
                qwp[qh][p][f] = (f32x2){qv[2*p][f], qv[2*p+1][f]};
    }

    float mrun[2][4];
    f32x2 psum[2][2];
    f32x4 acc[2][4];
    const f32x4 z4 = {0.f,0.f,0.f,0.f};
    #pragma unroll
    for(int qh=0;qh<2;++qh){
        #pragma unroll
        for(int j=0;j<4;++j) mrun[qh][j] = -3.0e38f;
        psum[qh][0] = (f32x2){0.f,0.f}; psum[qh][1] = (f32x2){0.f,0.f};
        #pragma unroll
        for(int t=0;t<4;++t) acc[qh][t] = z4;
    }

    for(int kt=0; kt<16; ++kt){
        const unsigned short* ktk = kbase + (size_t)(kt*64)*512;
        bf16x8 kf[4][2];
        #pragma unroll
        for(int t=0;t<4;++t)
            #pragma unroll
            for(int kk=0;kk<2;++kk)
                kf[t][kk] = *reinterpret_cast<const bf16x8*>(
                    ktk + (size_t)(t*16 + l15)*512 + kk*32 + lg*8);
        f32x4 kv[4];
        #pragma unroll
        for(int t=0;t<4;++t)
            kv[t] = *reinterpret_cast<const f32x4*>(kfb + (size_t)(kt*64 + t*16 + l15)*4);

        f32x4 s[2][4];
        #pragma unroll
        for(int qh=0;qh<2;++qh)
            #pragma unroll
            for(int t=0;t<4;++t) s[qh][t] = z4;
        #pragma unroll
        for(int t=0;t<4;++t)
            #pragma unroll
            for(int kk=0;kk<2;++kk)
                #pragma unroll
                for(int qh=0;qh<2;++qh)
                    s[qh][t] = __builtin_amdgcn_mfma_f32_16x16x32_bf16(qf[qh][kk], kf[t][kk], s[qh][t], 0, 0, 0);

        bf16x8 vf[4][2];
        #pragma unroll
        for(int t=0;t<4;++t)
            #pragma unroll
            for(int kk=0;kk<2;++kk)
                vf[t][kk] = *reinterpret_cast<const bf16x8*>(
                    vbase + (size_t)(t*16 + l15)*1024 + kt*64 + kk*32 + lg*8);

        #pragma unroll
        for(int t=0;t<4;++t){
            f32x2 c0 = {kv[t][0],kv[t][0]}, c1 = {kv[t][1],kv[t][1]},
                  c2 = {kv[t][2],kv[t][2]}, c3 = {kv[t][3],kv[t][3]};
            #pragma unroll
            for(int qh=0;qh<2;++qh){
                f32x2 b01 = qwp[qh][0][0]*c0 + qwp[qh][0][1]*c1 + qwp[qh][0][2]*c2 + c3;
                f32x2 b23 = qwp[qh][1][0]*c0 + qwp[qh][1][1]*c1 + qwp[qh][1][2]*c2 + c3;
                f32x2 s01 = {s[qh][t][0], s[qh][t][1]};
                f32x2 s23 = {s[qh][t][2], s[qh][t][3]};
                s01 = s01*SCALE2 + b01;
                s23 = s23*SCALE2 + b23;
                s[qh][t][0] = s01.x; s[qh][t][1] = s01.y;
                s[qh][t][2] = s23.x; s[qh][t][3] = s23.y;
            }
        }
        float pm[2][4];
        bool need = false;
        #pragma unroll
        for(int qh=0;qh<2;++qh)
            #pragma unroll
            for(int j=0;j<4;++j){
                float mx = fmaxf(fmaxf(s[qh][0][j], s[qh][1][j]), fmaxf(s[qh][2][j], s[qh][3][j]));
                mx = grp16_max(mx);
                pm[qh][j] = mx;
                need = need || (mx > mrun[qh][j] + THR);
            }
        if(__any(need ? 1 : 0)){
            #pragma unroll
            for(int qh=0;qh<2;++qh)
                #pragma unroll
                for(int j=0;j<4;++j){
                    float mn = fmaxf(mrun[qh][j], pm[qh][j]);
                    float scl = exp2f(mrun[qh][j] - mn);
                    mrun[qh][j] = mn;
                    if(j<2){ if(j==0) psum[qh][0].x *= scl; else psum[qh][0].y *= scl; }
                    else   { if(j==2) psum[qh][1].x *= scl; else psum[qh][1].y *= scl; }
                    #pragma unroll
                    for(int t=0;t<4;++t) acc[qh][t][j] *= scl;
                }
        }
        #pragma unroll
        for(int qh=0;qh<2;++qh){
            int row0 = qh*16 + lg*4;
            #pragma unroll
            for(int t=0;t<4;++t){
                float p0 = exp2f(s[qh][t][0] - mrun[qh][0]);
                float p1 = exp2f(s[qh][t][1] - mrun[qh][1]);
                float p2 = exp2f(s[qh][t][2] - mrun[qh][2]);
                float p3 = exp2f(s[qh][t][3] - mrun[qh][3]);
                psum[qh][0] += (f32x2){p0, p1};
                psum[qh][1] += (f32x2){p2, p3};
                unsigned w01 = cvtpk2(p0, p1);
                unsigned w23 = cvtpk2(p2, p3);
                int cb = (t*16 + l15)*2;
                *reinterpret_cast<unsigned short*>(Pw + swz(row0+0, cb)) = (unsigned short)w01;
                *reinterpret_cast<unsigned short*>(Pw + swz(row0+1, cb)) = (unsigned short)(w01 >> 16);
                *reinterpret_cast<unsigned short*>(Pw + swz(row0+2, cb)) = (unsigned short)w23;
                *reinterpret_cast<unsigned short*>(Pw + swz(row0+3, cb)) = (unsigned short)(w23 >> 16);
            }
        }
        #pragma unroll
        for(int kk=0;kk<2;++kk){
            #pragma unroll
            for(int qh=0;qh<2;++qh){
                bf16x8 pa = *reinterpret_cast<const bf16x8*>(Pw + swz(qh*16 + l15, kk*64 + lg*16));
                #pragma unroll
                for(int t=0;t<4;++t)
                    acc[qh][t] = __builtin_amdgcn_mfma_f32_16x16x32_bf16(pa, vf[t][kk], acc[qh][t], 0, 0, 0);
            }
        }
    }
    #pragma unroll
    for(int qh=0;qh<2;++qh){
        float rl[4];
        rl[0] = 1.0f / grp16_sum(psum[qh][0].x);
        rl[1] = 1.0f / grp16_sum(psum[qh][0].y);
        rl[2] = 1.0f / grp16_sum(psum[qh][1].x);
        rl[3] = 1.0f / grp16_sum(psum[qh][1].y);
        #pragma unroll
        for(int j=0;j<4;++j){
            int row = qbase + qh*16 + lg*4 + j;
            #pragma unroll
            for(int t=0;t<4;++t)
                ctxb[(size_t)row*512 + h*64 + t*16 + l15] = f2b(acc[qh][t][j] * rl[j]);
        }
    }
}

// ---------------------------------------------------------------------------
extern "C" void kernel_launch(void* const* d_in, const int* in_sizes, int n_in,
                              void* d_out, int out_size, void* d_ws, size_t ws_size,
                              hipStream_t stream){
    (void)in_sizes; (void)n_in; (void)out_size; (void)ws_size;
    const float* query     = (const float*)d_in[0];
    const float* key_value = (const float*)d_in[1];
    const float* query_pos = (const float*)d_in[2];
    const float* key_pos   = (const float*)d_in[3];
    const int*   key_mask  = (const int*)d_in[4];
    const float* Wq  = (const float*)d_in[5];
    const float* bq  = (const float*)d_in[6];
    const float* Wk  = (const float*)d_in[7];
    const float* bk  = (const float*)d_in[8];
    const float* Wv  = (const float*)d_in[9];
    const float* bv  = (const float*)d_in[10];
    const float* Wo  = (const float*)d_in[11];
    const float* bo  = (const float*)d_in[12];
    const float* Wqb = (const float*)d_in[13];
    const float* Wkb = (const float*)d_in[14];

    char* ws = (char*)d_ws;
    const size_t MB = 1048576;
    unsigned short* kp    = (unsigned short*)(ws);            // 32MB
    unsigned short* vpT   = (unsigned short*)(ws + 32*MB);    // 32MB
    unsigned short* qp    = (unsigned short*)(ws + 64*MB);    //  8MB
    unsigned short* kvb   = (unsigned short*)(ws + 72*MB);    // 16MB chunk buf
    unsigned short* ctxb  = (unsigned short*)(ws + 72*MB);    //  8MB (after kvb dies)
    unsigned short* WtQ   = (unsigned short*)(ws + 88*MB);    // 4 x 0.5MB
    unsigned short* WtK   = WtQ + 262144;
    unsigned short* WtV   = WtK + 262144;
    unsigned short* WtO   = WtV + 262144;
    float*          qwg   = (float*)(ws + 90*MB);             // 16KB
    float*          kfg   = (float*)(ws + 90*MB + 65536);     // 64KB
    // qb (bf16 query) lives in d_out's 16MB (dead before O-proj writes it)
    unsigned short* qb    = (unsigned short*)d_out;

    wt4_kernel<<<dim3(8,8,4), 256, 0, stream>>>(Wq, Wk, Wv, Wo, WtQ);
    posfeat_kernel<<<20, 256, 0, stream>>>(query_pos, key_pos, Wqb, Wkb, key_mask, qwg, kfg);

    // Q path: convert + project
    cvt_kernel<<<2048, 256, 0, stream>>>(query, qb, 524288);           // 4M elems
    gemm512g<0><<<256, 256, 0, stream>>>(qb, WtQ, bq, qp);

    // K/V path, 2 chunks of 16384 rows each
    for(int c=0; c<2; ++c){
        const float* kvc = key_value + (size_t)c*16384*512;
        cvt_kernel<<<2048, 256, 0, stream>>>(kvc, kvb, 1048576);       // 8M elems
        gemm512g<0><<<512, 256, 0, stream>>>(kvb, WtK, bk, kp + (size_t)c*16384*512);
        gemm512g<2><<<512, 256, 0, stream>>>(kvb, WtV, bv, vpT + (size_t)c*8388608);
    }

    attn4_kernel<<<512, 256, 0, stream>>>(qp, kp, vpT, qwg, kfg, ctxb);

    gemm512g<1><<<256, 256, 0, stream>>>(ctxb, WtO, bo, d_out);
}